// Round 1
// baseline (654.782 us; speedup 1.0000x reference)
//
#include <hip/hip_runtime.h>
#include <stdint.h>

// Problem dims (fixed by the reference): B=2048, T=512, F=64, H=16, 4H=64.
#define Bdim 2048
#define Tdim 512

typedef __attribute__((ext_vector_type(8))) short bf16x8;   // 8 bf16 in 4 VGPRs
typedef __attribute__((ext_vector_type(4))) float f32x4;

__device__ __forceinline__ short f2bf(float f) {
    // round-to-nearest-even fp32 -> bf16
    union { float f; uint32_t u; } v; v.f = f;
    uint32_t r = v.u + 0x7fffu + ((v.u >> 16) & 1u);
    return (short)(r >> 16);
}
__device__ __forceinline__ float bf2f(uint16_t s) {
    union { uint32_t u; float f; } v; v.u = ((uint32_t)s) << 16;
    return v.f;
}
__device__ __forceinline__ float rdlane(float v, int l) {
    return __int_as_float(__builtin_amdgcn_readlane(__float_as_int(v), l));
}

// Kernel 1: xz[bt][g] = sum_k x[bt][k] * Wx[k][g] + bias[g], stored bf16.
// M = B*T = 1M, N = 64, K = 64. One wave computes a 16x64 strip (8 MFMAs).
// Memory-bound: 256 MB read (x fp32) + 128 MB write (xz bf16).
__global__ __launch_bounds__(256) void xz_gemm(
    const float* __restrict__ x, const float* __restrict__ Wx,
    const float* __restrict__ bias, uint16_t* __restrict__ xz)
{
    const int lane = threadIdx.x & 63;
    const int wave = threadIdx.x >> 6;
    const int l15  = lane & 15;
    const int quad = lane >> 4;
    const size_t m0 = ((size_t)blockIdx.x * 4 + wave) * 16;

    // B fragments: B[k = kc*32 + quad*8 + j][n = nt*16 + l15]  (Wx row-major [K][N])
    bf16x8 bfrag[4][2];
    #pragma unroll
    for (int nt = 0; nt < 4; ++nt) {
        #pragma unroll
        for (int kc = 0; kc < 2; ++kc) {
            const float* src = Wx + (size_t)(kc * 32 + quad * 8) * 64 + nt * 16 + l15;
            #pragma unroll
            for (int j = 0; j < 8; ++j)
                bfrag[nt][kc][j] = f2bf(src[(size_t)j * 64]);
        }
    }

    // A fragments: A[m = l15][k = kc*32 + quad*8 + j]  (x row-major [M][64])
    bf16x8 afrag[2];
    #pragma unroll
    for (int kc = 0; kc < 2; ++kc) {
        const float* src = x + (m0 + l15) * 64 + kc * 32 + quad * 8;
        float4 p0 = *(const float4*)(src);
        float4 p1 = *(const float4*)(src + 4);
        afrag[kc][0] = f2bf(p0.x); afrag[kc][1] = f2bf(p0.y);
        afrag[kc][2] = f2bf(p0.z); afrag[kc][3] = f2bf(p0.w);
        afrag[kc][4] = f2bf(p1.x); afrag[kc][5] = f2bf(p1.y);
        afrag[kc][6] = f2bf(p1.z); afrag[kc][7] = f2bf(p1.w);
    }

    #pragma unroll
    for (int nt = 0; nt < 4; ++nt) {
        f32x4 acc = {0.f, 0.f, 0.f, 0.f};
        acc = __builtin_amdgcn_mfma_f32_16x16x32_bf16(afrag[0], bfrag[nt][0], acc, 0, 0, 0);
        acc = __builtin_amdgcn_mfma_f32_16x16x32_bf16(afrag[1], bfrag[nt][1], acc, 0, 0, 0);
        // C layout (measured m89/m91): col = lane&15, row = quad*4 + r
        const int col = nt * 16 + l15;
        const float bv = bias[col];
        #pragma unroll
        for (int r = 0; r < 4; ++r) {
            const size_t row = m0 + (size_t)(quad * 4 + r);
            xz[row * 64 + col] = (uint16_t)f2bf(acc[r] + bv);
        }
    }
}

// Kernel 2: sequential LSTM scan + MLP head. One wave per batch row.
// Lane g owns gate output g (0..63). h/c state: lane g holds the replicated
// value for hidden unit g&15; lanes 0..15 are the canonical copies, read back
// via v_readlane (wave-uniform h -> SGPR broadcast into the matvec FMAs).
__global__ __launch_bounds__(256) void lstm_scan(
    const uint16_t* __restrict__ xz, const float* __restrict__ Wh,
    const float* __restrict__ W2, const float* __restrict__ b2,
    const float* __restrict__ W3, const float* __restrict__ b3,
    const float* __restrict__ Wo, const float* __restrict__ bo,
    float* __restrict__ out)
{
    const int lane = threadIdx.x & 63;
    const int wave = threadIdx.x >> 6;
    const int b    = blockIdx.x * 4 + wave;
    const int j    = lane & 15;
    const int quad = lane >> 4;

    // Wh column g: wh[k] = Wh[k][lane], coalesced loads, cached after 1st block.
    float wh[16];
    #pragma unroll
    for (int k = 0; k < 16; ++k) wh[k] = Wh[(size_t)k * 64 + lane];

    const uint16_t* xp = xz + (size_t)b * (Tdim * 64) + lane;

    float c = 0.f, h = 0.f;

    #pragma unroll 8
    for (int t = 0; t < Tdim; ++t) {
        // z[g] = xz[b][t][g] + sum_k h[k] * Wh[k][g]; two FMA chains for ILP
        float acc0 = bf2f(xp[(size_t)t * 64]);
        float acc1 = 0.f;
        #pragma unroll
        for (int k = 0; k < 8; ++k) {
            acc0 = fmaf(rdlane(h, k),     wh[k],     acc0);
            acc1 = fmaf(rdlane(h, k + 8), wh[k + 8], acc1);
        }
        const float z = acc0 + acc1;
        // gates: lanes 0-15 i (sig), 16-31 f (sig), 32-47 g (relu), 48-63 o (sig)
        const float sig = 1.0f / (1.0f + __expf(-z));
        const float a = (quad == 2) ? fmaxf(z, 0.f) : sig;
        const float i_ = __shfl(a, j);
        const float f_ = __shfl(a, j + 16);
        const float g_ = __shfl(a, j + 32);
        const float o_ = __shfl(a, j + 48);
        c = f_ * c + i_ * g_;
        h = o_ * fmaxf(c, 0.f);   // h = o * relu(c_new)
    }

    // MLP head (tiny): gather h_T to uniform regs, compute on lane 0.
    float hh[16];
    #pragma unroll
    for (int k = 0; k < 16; ++k) hh[k] = rdlane(h, k);

    if (lane == 0) {
        float x2[8];
        #pragma unroll
        for (int k = 0; k < 8; ++k) {
            float s = b2[k];
            #pragma unroll
            for (int q = 0; q < 16; ++q) s = fmaf(hh[q], W2[(size_t)q * 8 + k], s);
            x2[k] = fmaxf(s, 0.f);
        }
        float x3[4];
        #pragma unroll
        for (int m = 0; m < 4; ++m) {
            float s = b3[m];
            #pragma unroll
            for (int k = 0; k < 8; ++k) s = fmaf(x2[k], W3[(size_t)k * 4 + m], s);
            x3[m] = fmaxf(s, 0.f);
        }
        float s = bo[0];
        #pragma unroll
        for (int m = 0; m < 4; ++m) s = fmaf(x3[m], Wo[m], s);
        out[b] = 1.0f / (1.0f + __expf(-s));
    }
}

extern "C" void kernel_launch(void* const* d_in, const int* in_sizes, int n_in,
                              void* d_out, int out_size, void* d_ws, size_t ws_size,
                              hipStream_t stream) {
    const float* x  = (const float*)d_in[0];
    const float* Wx = (const float*)d_in[1];
    const float* Wh = (const float*)d_in[2];
    const float* bb = (const float*)d_in[3];
    const float* W2 = (const float*)d_in[4];
    const float* b2 = (const float*)d_in[5];
    const float* W3 = (const float*)d_in[6];
    const float* b3 = (const float*)d_in[7];
    const float* Wo = (const float*)d_in[8];
    const float* bo = (const float*)d_in[9];

    uint16_t* xz = (uint16_t*)d_ws;   // needs B*T*64*2 = 128 MiB of workspace

    // GEMM: 1M rows / (4 waves * 16 rows) = 16384 blocks
    xz_gemm<<<(Bdim * Tdim) / 64, 256, 0, stream>>>(x, Wx, bb, xz);
    // Scan: 2048 rows / 4 waves = 512 blocks
    lstm_scan<<<Bdim / 4, 256, 0, stream>>>(xz, Wh, W2, b2, W3, b3, Wo, bo,
                                            (float*)d_out);
}

// Round 2
// 601.439 us; speedup vs baseline: 1.0887x; 1.0887x over previous
//
#include <hip/hip_runtime.h>
#include <stdint.h>

// Problem dims (fixed by the reference): B=2048, T=512, F=64, H=16, 4H=64.
#define Bdim 2048
#define Tdim 512

typedef __attribute__((ext_vector_type(8))) short bf16x8;   // 8 bf16 in 4 VGPRs
typedef __attribute__((ext_vector_type(4))) float f32x4;

struct ushort4_t { uint16_t x, y, z, w; };   // 8-byte POD, for dwordx2 ld/st

__device__ __forceinline__ uint16_t f2bf(float f) {
    // round-to-nearest-even fp32 -> bf16
    union { float f; uint32_t u; } v; v.f = f;
    uint32_t r = v.u + 0x7fffu + ((v.u >> 16) & 1u);
    return (uint16_t)(r >> 16);
}
__device__ __forceinline__ float bf2f(uint16_t s) {
    union { uint32_t u; float f; } v; v.u = ((uint32_t)s) << 16;
    return v.f;
}
__device__ __forceinline__ float sigmoidf(float z) {
    return __builtin_amdgcn_rcpf(1.0f + __expf(-z));
}

// Kernel 1: z = x @ Wx + b, M = B*T = 1M rows, N = 64, K = 64.
// Computed TRANSPOSED via MFMA (D = Wx^T * x^T) so each lane's 16 outputs lie
// in ONE output row -> packed ushort4 stores (fixes the 2-byte-scatter store
// disaster of round 1). Output layout is gate-interleaved for the scan:
//   xz[bt][j][gate], gate in {i,f,g,o}, j = hidden unit 0..15  (128 B/row)
__global__ __launch_bounds__(256) void xz_gemm(
    const float* __restrict__ x, const float* __restrict__ Wx,
    const float* __restrict__ bias, uint16_t* __restrict__ xz)
{
    const int lane = threadIdx.x & 63;
    const int wave = threadIdx.x >> 6;
    const int l15  = lane & 15;
    const int quad = lane >> 4;
    const size_t m0 = ((size_t)blockIdx.x * 4 + wave) * 16;

    // "A" operand = Wx^T tile: A[m = nt*16 + l15][k = kc*32 + quad*8 + j]
    bf16x8 wfrag[4][2];
    #pragma unroll
    for (int nt = 0; nt < 4; ++nt) {
        #pragma unroll
        for (int kc = 0; kc < 2; ++kc) {
            const float* src = Wx + (size_t)(kc * 32 + quad * 8) * 64 + nt * 16 + l15;
            #pragma unroll
            for (int j = 0; j < 8; ++j)
                wfrag[nt][kc][j] = (short)f2bf(src[(size_t)j * 64]);
        }
    }

    // "B" operand = x^T: B[k = kc*32 + quad*8 + j][n = l15] = x[m0+l15][k]
    bf16x8 xfrag[2];
    #pragma unroll
    for (int kc = 0; kc < 2; ++kc) {
        const float* src = x + (m0 + l15) * 64 + kc * 32 + quad * 8;
        float4 p0 = *(const float4*)(src);
        float4 p1 = *(const float4*)(src + 4);
        xfrag[kc][0] = (short)f2bf(p0.x); xfrag[kc][1] = (short)f2bf(p0.y);
        xfrag[kc][2] = (short)f2bf(p0.z); xfrag[kc][3] = (short)f2bf(p0.w);
        xfrag[kc][4] = (short)f2bf(p1.x); xfrag[kc][5] = (short)f2bf(p1.y);
        xfrag[kc][6] = (short)f2bf(p1.z); xfrag[kc][7] = (short)f2bf(p1.w);
    }

    // D[g = nt*16 + quad*4 + r][m-col = l15] = z[m0+l15][g]
    f32x4 acc[4];
    #pragma unroll
    for (int nt = 0; nt < 4; ++nt) {
        f32x4 a = {0.f, 0.f, 0.f, 0.f};
        a = __builtin_amdgcn_mfma_f32_16x16x32_bf16(wfrag[nt][0], xfrag[0], a, 0, 0, 0);
        a = __builtin_amdgcn_mfma_f32_16x16x32_bf16(wfrag[nt][1], xfrag[1], a, 0, 0, 0);
        acc[nt] = a;
    }

    // bias[g] for g = nt*16 + quad*4 + r  -> float4 per nt, component r
    float4 bv[4];
    #pragma unroll
    for (int nt = 0; nt < 4; ++nt)
        bv[nt] = *(const float4*)(bias + nt * 16 + quad * 4);

    // Lane's 16 values all belong to output row m0+l15.
    // g = nt*16 + quad*4 + r  ->  unit j = quad*4+r, gate = nt
    // permuted pos = j*4 + gate  ->  ushort4 over nt at elem (quad*4+r)*4
    ushort4_t* rowp = (ushort4_t*)(xz + (m0 + l15) * 64);
    #pragma unroll
    for (int r = 0; r < 4; ++r) {
        const float* b0 = (const float*)&bv[0];
        const float* b1 = (const float*)&bv[1];
        const float* b2 = (const float*)&bv[2];
        const float* b3 = (const float*)&bv[3];
        ushort4_t o;
        o.x = f2bf(acc[0][r] + b0[r]);   // i
        o.y = f2bf(acc[1][r] + b1[r]);   // f
        o.z = f2bf(acc[2][r] + b2[r]);   // g
        o.w = f2bf(acc[3][r] + b3[r]);   // o
        rowp[quad * 4 + r] = o;
    }
}

// Kernel 2: LSTM scan + MLP head. One wave = 4 batch rows, 16 lanes/row.
// Lane (r = lane>>4, j = lane&15) owns hidden unit j of row b0+r and computes
// ALL FOUR gates of that unit -> i,f,g,o are in-lane (no gather shuffles).
// Only cross-lane op: broadcast h[0..15] of own row (16 pipelined bpermutes)
// at the top of each step. 4 independent 16-FMA chains give 4-way ILP.
__global__ __launch_bounds__(64) void lstm_scan(
    const uint16_t* __restrict__ xz, const float* __restrict__ Wh,
    const float* __restrict__ W2, const float* __restrict__ b2,
    const float* __restrict__ W3, const float* __restrict__ b3,
    const float* __restrict__ Wo, const float* __restrict__ bo,
    float* __restrict__ out)
{
    const int lane = threadIdx.x & 63;
    const int r    = lane >> 4;
    const int j    = lane & 15;
    const int base = lane & 48;            // first lane of my 16-lane group
    const int b0   = blockIdx.x * 4;

    // Wh[k][gate*16 + j] for all k, per gate. 4 KB table, L1-cached.
    float wi[16], wf[16], wg[16], wo[16];
    #pragma unroll
    for (int k = 0; k < 16; ++k) {
        const float* row = Wh + (size_t)k * 64 + j;
        wi[k] = row[0];
        wf[k] = row[16];
        wg[k] = row[32];
        wo[k] = row[48];
    }

    // xz is gate-interleaved: ushort4 {i,f,g,o} per unit j. 8 B/lane/step.
    const ushort4_t* xp =
        (const ushort4_t*)xz + ((size_t)(b0 + r) * Tdim) * 16 + j;

    float c = 0.f, h = 0.f;

    ushort4_t cur[8], nxt[8];
    #pragma unroll
    for (int u = 0; u < 8; ++u) { cur[u] = xp[(size_t)u * 16]; nxt[u] = cur[u]; }

    for (int tb = 0; tb < Tdim; tb += 8) {
        const bool more = (tb + 8) < Tdim;
        #pragma unroll
        for (int u = 0; u < 8; ++u)
            if (more) nxt[u] = xp[(size_t)(tb + 8 + u) * 16];

        #pragma unroll
        for (int u = 0; u < 8; ++u) {
            // broadcast my row's h vector (pipelined, independent bpermutes)
            float hk[16];
            #pragma unroll
            for (int k = 0; k < 16; ++k) hk[k] = __shfl(h, base + k);

            const ushort4_t q = cur[u];
            float zi = bf2f(q.x), zf = bf2f(q.y), zg = bf2f(q.z), zo = bf2f(q.w);
            #pragma unroll
            for (int k = 0; k < 16; ++k) {
                zi = fmaf(hk[k], wi[k], zi);
                zf = fmaf(hk[k], wf[k], zf);
                zg = fmaf(hk[k], wg[k], zg);
                zo = fmaf(hk[k], wo[k], zo);
            }
            const float i_ = sigmoidf(zi);
            const float f_ = sigmoidf(zf);
            const float o_ = sigmoidf(zo);
            const float g_ = fmaxf(zg, 0.f);
            c = fmaf(f_, c, i_ * g_);
            h = o_ * fmaxf(c, 0.f);
        }
        #pragma unroll
        for (int u = 0; u < 8; ++u) cur[u] = nxt[u];
    }

    // MLP head: gather my row's h_T, lanes j==0 compute the scalar head.
    float hh[16];
    #pragma unroll
    for (int k = 0; k < 16; ++k) hh[k] = __shfl(h, base + k);

    if (j == 0) {
        float x2[8];
        #pragma unroll
        for (int k = 0; k < 8; ++k) {
            float s = b2[k];
            #pragma unroll
            for (int q = 0; q < 16; ++q) s = fmaf(hh[q], W2[(size_t)q * 8 + k], s);
            x2[k] = fmaxf(s, 0.f);
        }
        float x3[4];
        #pragma unroll
        for (int m = 0; m < 4; ++m) {
            float s = b3[m];
            #pragma unroll
            for (int k = 0; k < 8; ++k) s = fmaf(x2[k], W3[(size_t)k * 4 + m], s);
            x3[m] = fmaxf(s, 0.f);
        }
        float s = bo[0];
        #pragma unroll
        for (int m = 0; m < 4; ++m) s = fmaf(x3[m], Wo[m], s);
        out[b0 + r] = sigmoidf(s);
    }
}

extern "C" void kernel_launch(void* const* d_in, const int* in_sizes, int n_in,
                              void* d_out, int out_size, void* d_ws, size_t ws_size,
                              hipStream_t stream) {
    const float* x  = (const float*)d_in[0];
    const float* Wx = (const float*)d_in[1];
    const float* Wh = (const float*)d_in[2];
    const float* bb = (const float*)d_in[3];
    const float* W2 = (const float*)d_in[4];
    const float* b2 = (const float*)d_in[5];
    const float* W3 = (const float*)d_in[6];
    const float* b3 = (const float*)d_in[7];
    const float* Wo = (const float*)d_in[8];
    const float* bo = (const float*)d_in[9];

    uint16_t* xz = (uint16_t*)d_ws;   // B*T*64*2 = 128 MiB of workspace

    // GEMM: 1M rows / (4 waves * 16 rows) = 16384 blocks
    xz_gemm<<<(Bdim * Tdim) / 64, 256, 0, stream>>>(x, Wx, bb, xz);
    // Scan: 2048 rows / 4 rows-per-wave = 512 single-wave blocks
    lstm_scan<<<Bdim / 4, 64, 0, stream>>>(xz, Wh, W2, b2, W3, b3, Wo, bo,
                                           (float*)d_out);
}

// Round 3
// 450.398 us; speedup vs baseline: 1.4538x; 1.3353x over previous
//
#include <hip/hip_runtime.h>
#include <stdint.h>

// Problem dims (fixed by the reference): B=2048, T=512, F=64, H=16, 4H=64.
#define Bdim 2048
#define Tdim 512
#define NBLK (Tdim / 16)            // 32 time blocks of 16 steps

// LDS z-staging layout (fp32): [buf 2][row 4][t 16][unit 16][gate 4], padded.
#define TSTRIDE 68                  // dwords per (row,t): 64 + 4 pad
#define RSTRIDE (16 * TSTRIDE + 8)  // 1096 dwords per batch row (+8: bank spread)
#define BUFD (4 * RSTRIDE)          // 4384 dwords per buffer

typedef __attribute__((ext_vector_type(8))) short bf16x8;   // 8 bf16, 4 VGPRs
typedef __attribute__((ext_vector_type(4))) float f32x4;

__device__ __forceinline__ uint16_t f2bf(float f) {
    // round-to-nearest-even fp32 -> bf16
    union { float f; uint32_t u; } v; v.f = f;
    uint32_t r = v.u + 0x7fffu + ((v.u >> 16) & 1u);
    return (uint16_t)(r >> 16);
}
__device__ __forceinline__ float sigmoidf(float z) {
    return __builtin_amdgcn_rcpf(1.0f + __expf(-z));
}

// One wave (64 threads) per block; 4 batch rows per wave.
// Scan role:   lane = (r = lane>>4, j = lane&15) owns hidden unit j of row b0+r;
//              all 4 gates of that unit computed in-lane (no gather shuffles).
// Project role: per 16-step time block, the SAME wave computes the next block's
//              z = x@Wx + b with 32 MFMAs (matrix pipe, overlaps scan VALU work)
//              into the other half of a double-buffered LDS staging area.
__global__ __launch_bounds__(64, 1) void lstm_fused(
    const float* __restrict__ x, const float* __restrict__ Wx,
    const float* __restrict__ bias, const float* __restrict__ Wh,
    const float* __restrict__ W2, const float* __restrict__ b2,
    const float* __restrict__ W3, const float* __restrict__ b3,
    const float* __restrict__ Wo, const float* __restrict__ bo,
    float* __restrict__ out)
{
    __shared__ __align__(16) float zbuf[2 * BUFD];

    const int lane = threadIdx.x;        // single wave
    const int l15  = lane & 15;
    const int quad = lane >> 4;
    const int r    = quad;               // scan: batch sub-row
    const int j    = l15;                // scan: hidden unit
    const int base = lane & 48;          // first lane of my 16-lane group
    const int b0   = blockIdx.x * 4;

    // ---- Wh columns for my unit's 4 gates (loaded once, 4 KB table) ----
    float wi[16], wf[16], wg[16], wo_[16];
    #pragma unroll
    for (int k = 0; k < 16; ++k) {
        const float* row = Wh + (size_t)k * 64 + j;
        wi[k]  = row[0];
        wf[k]  = row[16];
        wg[k]  = row[32];
        wo_[k] = row[48];
    }

    // ---- Wx as MFMA B-fragments (bf16), loaded once ----
    // B[k = kc*32 + quad*8 + jj][n = nt*16 + l15] = Wx[k][n]
    bf16x8 wxf[4][2];
    #pragma unroll
    for (int nt = 0; nt < 4; ++nt)
        #pragma unroll
        for (int kc = 0; kc < 2; ++kc)
            #pragma unroll
            for (int jj = 0; jj < 8; ++jj)
                wxf[nt][kc][jj] =
                    (short)f2bf(Wx[(size_t)(kc * 32 + quad * 8 + jj) * 64 + nt * 16 + l15]);

    // bias per lane: gate column g = nt*16 + l15 (constant over the 4 t-regs)
    float bv[4];
    #pragma unroll
    for (int nt = 0; nt < 4; ++nt) bv[nt] = bias[nt * 16 + l15];

    // ---- x tile staging registers: [row][kc][half], 16 float4 ----
    float4 xn[4][2][2];
    auto load_tile = [&](int t0) {
        #pragma unroll
        for (int rr = 0; rr < 4; ++rr) {
            const float* p = x + ((size_t)(b0 + rr) * Tdim + t0 + l15) * 64 + quad * 8;
            xn[rr][0][0] = *(const float4*)(p);
            xn[rr][0][1] = *(const float4*)(p + 4);
            xn[rr][1][0] = *(const float4*)(p + 32);
            xn[rr][1][1] = *(const float4*)(p + 36);
        }
    };

    // Project current xn (one 16-step tile, 4 rows) into LDS buffer q.
    // A = x tile (m = t_local), B = Wx (n = gate col). Verified D layout:
    // D[m = quad*4 + reg][n = nt*16 + l15]  ->  t = quad*4+reg, unit = l15,
    // gate = nt. {i,f,g,o} of (t, unit) are acc[0..3][reg] -> one b128 write.
    auto project = [&](int q) {
        #pragma unroll
        for (int rr = 0; rr < 4; ++rr) {
            bf16x8 af[2];
            #pragma unroll
            for (int kc = 0; kc < 2; ++kc) {
                const float4 p0 = xn[rr][kc][0], p1 = xn[rr][kc][1];
                af[kc][0] = (short)f2bf(p0.x); af[kc][1] = (short)f2bf(p0.y);
                af[kc][2] = (short)f2bf(p0.z); af[kc][3] = (short)f2bf(p0.w);
                af[kc][4] = (short)f2bf(p1.x); af[kc][5] = (short)f2bf(p1.y);
                af[kc][6] = (short)f2bf(p1.z); af[kc][7] = (short)f2bf(p1.w);
            }
            f32x4 acc[4];
            #pragma unroll
            for (int nt = 0; nt < 4; ++nt) {
                f32x4 a = {bv[nt], bv[nt], bv[nt], bv[nt]};
                a = __builtin_amdgcn_mfma_f32_16x16x32_bf16(af[0], wxf[nt][0], a, 0, 0, 0);
                a = __builtin_amdgcn_mfma_f32_16x16x32_bf16(af[1], wxf[nt][1], a, 0, 0, 0);
                acc[nt] = a;
            }
            #pragma unroll
            for (int reg = 0; reg < 4; ++reg) {
                float4 w4;
                w4.x = acc[0][reg]; w4.y = acc[1][reg];
                w4.z = acc[2][reg]; w4.w = acc[3][reg];
                *(float4*)&zbuf[q * BUFD + rr * RSTRIDE +
                                (quad * 4 + reg) * TSTRIDE + l15 * 4] = w4;
            }
        }
    };

    const int zoff = r * RSTRIDE + j * 4;   // scan-side lane-constant offset
    auto readz = [&](int q, int t) -> float4 {
        return *(const float4*)&zbuf[q * BUFD + zoff + t * TSTRIDE];
    };

    // ---- prologue: block 0 projected, block 1 loads in flight ----
    load_tile(0);
    project(0);
    load_tile(16);

    float c = 0.f, h = 0.f;
    float4 zc = readz(0, 0);

    for (int n = 0; n < NBLK; ++n) {
        const int p = n & 1;
        if (n + 1 < NBLK) {
            project(p ^ 1);                         // consumes xn = tile n+1
            if (n + 2 < NBLK) load_tile((n + 2) * 16);  // prefetch, 16 steps slack
        }
        #pragma unroll
        for (int u = 0; u < 16; ++u) {
            // prefetch next step's z (last step: next block's t=0, other buffer)
            float4 zn = (u < 15) ? readz(p, u + 1) : readz(p ^ 1, 0);

            // broadcast my row's h vector (16 independent bpermutes)
            float hk[16];
            #pragma unroll
            for (int k = 0; k < 16; ++k) hk[k] = __shfl(h, base + k);

            float zi = zc.x, zf = zc.y, zg = zc.z, zo = zc.w;
            #pragma unroll
            for (int k = 0; k < 16; ++k) {
                zi = fmaf(hk[k], wi[k],  zi);
                zf = fmaf(hk[k], wf[k],  zf);
                zg = fmaf(hk[k], wg[k],  zg);
                zo = fmaf(hk[k], wo_[k], zo);
            }
            const float i_ = sigmoidf(zi);
            const float f_ = sigmoidf(zf);
            const float o_ = sigmoidf(zo);
            const float g_ = fmaxf(zg, 0.f);
            c = fmaf(f_, c, i_ * g_);
            h = o_ * fmaxf(c, 0.f);    // h = o * relu(c_new)
            zc = zn;
        }
    }

    // ---- MLP head: gather my row's h_T; lanes j==0 compute the scalar head ----
    float hh[16];
    #pragma unroll
    for (int k = 0; k < 16; ++k) hh[k] = __shfl(h, base + k);

    if (j == 0) {
        float x2[8];
        #pragma unroll
        for (int k = 0; k < 8; ++k) {
            float s = b2[k];
            #pragma unroll
            for (int q = 0; q < 16; ++q) s = fmaf(hh[q], W2[(size_t)q * 8 + k], s);
            x2[k] = fmaxf(s, 0.f);
        }
        float x3[4];
        #pragma unroll
        for (int m = 0; m < 4; ++m) {
            float s = b3[m];
            #pragma unroll
            for (int k = 0; k < 8; ++k) s = fmaf(x2[k], W3[(size_t)k * 4 + m], s);
            x3[m] = fmaxf(s, 0.f);
        }
        float s = bo[0];
        #pragma unroll
        for (int m = 0; m < 4; ++m) s = fmaf(x3[m], Wo[m], s);
        out[b0 + r] = sigmoidf(s);
    }
}

extern "C" void kernel_launch(void* const* d_in, const int* in_sizes, int n_in,
                              void* d_out, int out_size, void* d_ws, size_t ws_size,
                              hipStream_t stream) {
    const float* x  = (const float*)d_in[0];
    const float* Wx = (const float*)d_in[1];
    const float* Wh = (const float*)d_in[2];
    const float* bb = (const float*)d_in[3];
    const float* W2 = (const float*)d_in[4];
    const float* b2 = (const float*)d_in[5];
    const float* W3 = (const float*)d_in[6];
    const float* b3 = (const float*)d_in[7];
    const float* Wo = (const float*)d_in[8];
    const float* bo = (const float*)d_in[9];

    // Single fused kernel: 2048 rows / 4 rows-per-wave = 512 one-wave blocks.
    // No workspace needed (xz round-trip eliminated).
    lstm_fused<<<Bdim / 4, 64, 0, stream>>>(x, Wx, bb, Wh, W2, b2, W3, b3,
                                            Wo, bo, (float*)d_out);
}

// Round 4
// 407.219 us; speedup vs baseline: 1.6079x; 1.1060x over previous
//
#include <hip/hip_runtime.h>
#include <stdint.h>

// Problem dims (fixed by the reference): B=2048, T=512, F=64, H=16, 4H=64.
#define Bdim 2048
#define Tdim 512
#define NBLK (Tdim / 16)            // 32 time blocks of 16 steps

// LDS z-staging layout (fp32): [buf 2][row 4][t 16][unit 16][gate 4], padded.
#define TSTRIDE 68                  // dwords per (row,t): 64 + 4 pad
#define RSTRIDE (16 * TSTRIDE + 8)  // 1096 dwords per batch row (+8: bank spread)
#define BUFD (4 * RSTRIDE)          // 4384 dwords per buffer
#define HSTRIDE 20                  // h-table row stride: 4 rows land on
                                    // disjoint bank quads for b128 reads

typedef __attribute__((ext_vector_type(8))) short bf16x8;   // 8 bf16, 4 VGPRs
typedef __attribute__((ext_vector_type(4))) float f32x4;

__device__ __forceinline__ uint16_t f2bf(float f) {
    // round-to-nearest-even fp32 -> bf16
    union { float f; uint32_t u; } v; v.f = f;
    uint32_t r = v.u + 0x7fffu + ((v.u >> 16) & 1u);
    return (uint16_t)(r >> 16);
}
__device__ __forceinline__ float sigmoidf(float z) {
    return __builtin_amdgcn_rcpf(1.0f + __expf(-z));
}

// One wave (64 threads) per block; 4 batch rows per wave.
// Scan role:    lane (r = lane>>4, j = lane&15) owns hidden unit j of row b0+r;
//               all 4 gates of that unit computed in-lane.
// h broadcast:  1 ds_write_b32 + 4 ds_read_b128 per step via hbuf (replaces 16
//               bpermutes; in-order DS pipe makes write->read safe, no barrier).
// Project role: per 16-step block, the SAME wave computes the next block's
//               z = x@Wx + b with 32 MFMAs into double-buffered LDS.
__global__ __launch_bounds__(64, 1) void lstm_fused(
    const float* __restrict__ x, const float* __restrict__ Wx,
    const float* __restrict__ bias, const float* __restrict__ Wh,
    const float* __restrict__ W2, const float* __restrict__ b2,
    const float* __restrict__ W3, const float* __restrict__ b3,
    const float* __restrict__ Wo, const float* __restrict__ bo,
    float* __restrict__ out)
{
    __shared__ __align__(16) float zbuf[2 * BUFD];
    __shared__ __align__(16) float hbuf[4 * HSTRIDE];

    const int lane = threadIdx.x;        // single wave
    const int l15  = lane & 15;
    const int quad = lane >> 4;
    const int r    = quad;               // scan: batch sub-row
    const int j    = l15;                // scan: hidden unit
    const int b0   = blockIdx.x * 4;

    // ---- Wh columns for my unit's 4 gates (loaded once, 4 KB table) ----
    float wi[16], wf[16], wg[16], wo_[16];
    #pragma unroll
    for (int k = 0; k < 16; ++k) {
        const float* row = Wh + (size_t)k * 64 + j;
        wi[k]  = row[0];
        wf[k]  = row[16];
        wg[k]  = row[32];
        wo_[k] = row[48];
    }

    // ---- Wx as MFMA B-fragments (bf16), loaded once ----
    // B[k = kc*32 + quad*8 + jj][n = nt*16 + l15] = Wx[k][n]
    bf16x8 wxf[4][2];
    #pragma unroll
    for (int nt = 0; nt < 4; ++nt)
        #pragma unroll
        for (int kc = 0; kc < 2; ++kc)
            #pragma unroll
            for (int jj = 0; jj < 8; ++jj)
                wxf[nt][kc][jj] =
                    (short)f2bf(Wx[(size_t)(kc * 32 + quad * 8 + jj) * 64 + nt * 16 + l15]);

    // bias per lane: gate column g = nt*16 + l15 (constant over the 4 t-regs)
    float bv[4];
    #pragma unroll
    for (int nt = 0; nt < 4; ++nt) bv[nt] = bias[nt * 16 + l15];

    // ---- x tile staging registers: [row][kc][half], 16 float4 ----
    float4 xn[4][2][2];
    auto load_tile = [&](int t0) {
        #pragma unroll
        for (int rr = 0; rr < 4; ++rr) {
            const float* p = x + ((size_t)(b0 + rr) * Tdim + t0 + l15) * 64 + quad * 8;
            xn[rr][0][0] = *(const float4*)(p);
            xn[rr][0][1] = *(const float4*)(p + 4);
            xn[rr][1][0] = *(const float4*)(p + 32);
            xn[rr][1][1] = *(const float4*)(p + 36);
        }
    };

    // Project current xn (one 16-step tile, 4 rows) into LDS buffer q.
    // D[m = quad*4 + reg][n = nt*16 + l15] -> t = quad*4+reg, unit = l15,
    // gate = nt. {i,f,g,o} of (t, unit) are acc[0..3][reg] -> one b128 write.
    auto project = [&](int q) {
        #pragma unroll
        for (int rr = 0; rr < 4; ++rr) {
            bf16x8 af[2];
            #pragma unroll
            for (int kc = 0; kc < 2; ++kc) {
                const float4 p0 = xn[rr][kc][0], p1 = xn[rr][kc][1];
                af[kc][0] = (short)f2bf(p0.x); af[kc][1] = (short)f2bf(p0.y);
                af[kc][2] = (short)f2bf(p0.z); af[kc][3] = (short)f2bf(p0.w);
                af[kc][4] = (short)f2bf(p1.x); af[kc][5] = (short)f2bf(p1.y);
                af[kc][6] = (short)f2bf(p1.z); af[kc][7] = (short)f2bf(p1.w);
            }
            f32x4 acc[4];
            #pragma unroll
            for (int nt = 0; nt < 4; ++nt) {
                f32x4 a = {bv[nt], bv[nt], bv[nt], bv[nt]};
                a = __builtin_amdgcn_mfma_f32_16x16x32_bf16(af[0], wxf[nt][0], a, 0, 0, 0);
                a = __builtin_amdgcn_mfma_f32_16x16x32_bf16(af[1], wxf[nt][1], a, 0, 0, 0);
                acc[nt] = a;
            }
            #pragma unroll
            for (int reg = 0; reg < 4; ++reg) {
                float4 w4;
                w4.x = acc[0][reg]; w4.y = acc[1][reg];
                w4.z = acc[2][reg]; w4.w = acc[3][reg];
                *(float4*)&zbuf[q * BUFD + rr * RSTRIDE +
                                (quad * 4 + reg) * TSTRIDE + l15 * 4] = w4;
            }
        }
    };

    const int zoff = r * RSTRIDE + j * 4;   // scan-side lane-constant offset
    auto readz = [&](int q, int t) -> float4 {
        return *(const float4*)&zbuf[q * BUFD + zoff + t * TSTRIDE];
    };

    // ---- prologue: block 0 projected, block 1 loads in flight ----
    load_tile(0);
    project(0);
    load_tile(16);

    float c = 0.f, h = 0.f;
    float hk[16];
    #pragma unroll
    for (int k = 0; k < 16; ++k) hk[k] = 0.f;   // h0 = 0
    float4 zc = readz(0, 0);

    for (int n = 0; n < NBLK; ++n) {
        const int p = n & 1;
        if (n + 1 < NBLK) {
            project(p ^ 1);                          // consumes xn = tile n+1
            if (n + 2 < NBLK) load_tile((n + 2) * 16);  // prefetch, 16 steps slack
        }
        #pragma unroll
        for (int u = 0; u < 16; ++u) {
            // prefetch next step's z (last step: next block's t=0, other buffer)
            float4 zn = (u < 15) ? readz(p, u + 1) : readz(p ^ 1, 0);

            float zi = zc.x, zf = zc.y, zg = zc.z, zo = zc.w;
            #pragma unroll
            for (int k = 0; k < 16; ++k) {
                zi = fmaf(hk[k], wi[k],  zi);
                zf = fmaf(hk[k], wf[k],  zf);
                zg = fmaf(hk[k], wg[k],  zg);
                zo = fmaf(hk[k], wo_[k], zo);
            }
            const float i_ = sigmoidf(zi);
            const float f_ = sigmoidf(zf);
            const float o_ = sigmoidf(zo);
            const float g_ = fmaxf(zg, 0.f);
            c = fmaf(f_, c, i_ * g_);
            h = o_ * fmaxf(c, 0.f);    // h = o * relu(c_new)

            // broadcast h: 1 write + 4 b128 reads (DS pipe is in-order per
            // wave, so the reads see this step's writes from all lanes).
            hbuf[r * HSTRIDE + j] = h;
            const float4* hb = (const float4*)&hbuf[r * HSTRIDE];
            float4 h0 = hb[0], h1 = hb[1], h2 = hb[2], h3 = hb[3];
            hk[0]  = h0.x; hk[1]  = h0.y; hk[2]  = h0.z; hk[3]  = h0.w;
            hk[4]  = h1.x; hk[5]  = h1.y; hk[6]  = h1.z; hk[7]  = h1.w;
            hk[8]  = h2.x; hk[9]  = h2.y; hk[10] = h2.z; hk[11] = h2.w;
            hk[12] = h3.x; hk[13] = h3.y; hk[14] = h3.z; hk[15] = h3.w;

            zc = zn;
        }
    }

    // ---- MLP head: hk already holds my row's full h_T (from last broadcast) ----
    if (j == 0) {
        float x2[8];
        #pragma unroll
        for (int k = 0; k < 8; ++k) {
            float s = b2[k];
            #pragma unroll
            for (int q = 0; q < 16; ++q) s = fmaf(hk[q], W2[(size_t)q * 8 + k], s);
            x2[k] = fmaxf(s, 0.f);
        }
        float x3[4];
        #pragma unroll
        for (int m = 0; m < 4; ++m) {
            float s = b3[m];
            #pragma unroll
            for (int k = 0; k < 8; ++k) s = fmaf(x2[k], W3[(size_t)k * 4 + m], s);
            x3[m] = fmaxf(s, 0.f);
        }
        float s = bo[0];
        #pragma unroll
        for (int m = 0; m < 4; ++m) s = fmaf(x3[m], Wo[m], s);
        out[b0 + r] = sigmoidf(s);
    }
}

extern "C" void kernel_launch(void* const* d_in, const int* in_sizes, int n_in,
                              void* d_out, int out_size, void* d_ws, size_t ws_size,
                              hipStream_t stream) {
    const float* x  = (const float*)d_in[0];
    const float* Wx = (const float*)d_in[1];
    const float* Wh = (const float*)d_in[2];
    const float* bb = (const float*)d_in[3];
    const float* W2 = (const float*)d_in[4];
    const float* b2 = (const float*)d_in[5];
    const float* W3 = (const float*)d_in[6];
    const float* b3 = (const float*)d_in[7];
    const float* Wo = (const float*)d_in[8];
    const float* bo = (const float*)d_in[9];

    // Single fused kernel: 2048 rows / 4 rows-per-wave = 512 one-wave blocks.
    lstm_fused<<<Bdim / 4, 64, 0, stream>>>(x, Wx, bb, Wh, W2, b2, W3, b3,
                                            Wo, bo, (float*)d_out);
}

// Round 5
// 388.061 us; speedup vs baseline: 1.6873x; 1.0494x over previous
//
#include <hip/hip_runtime.h>
#include <stdint.h>

// Problem dims (fixed by the reference): B=2048, T=512, F=64, H=16, 4H=64.
#define Bdim 2048
#define Tdim 512
#define NBLK (Tdim / 16)            // 32 time blocks of 16 steps

// LDS z-staging (fp32), ONE batch row per block now:
// [buf 2][t 16][unit 16][gate 4] with +4 dword pad per t-row.
#define TSTRIDE 68                  // dwords per t: 64 + 4 pad
#define BUFD (16 * TSTRIDE)         // 1088 dwords per buffer (~4.3 KB)

typedef __attribute__((ext_vector_type(8))) short bf16x8;   // 8 bf16, 4 VGPRs
typedef __attribute__((ext_vector_type(4))) float f32x4;

__device__ __forceinline__ uint16_t f2bf(float f) {
    // round-to-nearest-even fp32 -> bf16
    union { float f; uint32_t u; } v; v.f = f;
    uint32_t r = v.u + 0x7fffu + ((v.u >> 16) & 1u);
    return (uint16_t)(r >> 16);
}
__device__ __forceinline__ float sigmoidf(float z) {
    return __builtin_amdgcn_rcpf(1.0f + __expf(-z));
}

// One wave (64 threads) per block, ONE batch row per wave (2048 waves total ->
// 2 waves/SIMD machine-wide, 4x the co-resident chains of round 4).
// Lane (g = lane>>4, j = lane&15) owns gate g of hidden unit j:
//   - per step: one 16-FMA dot (2 independent 8-chains) for z[g*16+j]
//   - gate gather: 4 __shfl (i,f,g,o of unit j from lanes j+16g)
//   - c,h updated replicated in all 4 quads (bit-identical)
//   - h broadcast: 1 ds_write (4 same-value writers/address) + 4 ds_read_b128
// Projection: same wave computes next 16-step block's z = x@Wx + b with
// 8 MFMAs into double-buffered LDS (matrix pipe overlaps scan VALU).
__global__ __launch_bounds__(64, 2) void lstm_fused(
    const float* __restrict__ x, const float* __restrict__ Wx,
    const float* __restrict__ bias, const float* __restrict__ Wh,
    const float* __restrict__ W2, const float* __restrict__ b2,
    const float* __restrict__ W3, const float* __restrict__ b3,
    const float* __restrict__ Wo, const float* __restrict__ bo,
    float* __restrict__ out)
{
    __shared__ __align__(16) float zbuf[2 * BUFD];
    __shared__ __align__(16) float hbuf[16];

    const int lane = threadIdx.x;        // single wave
    const int l15  = lane & 15;          // hidden unit j
    const int quad = lane >> 4;          // gate g: 0=i 1=f 2=g 3=o
    const int b    = blockIdx.x;

    // ---- my gate column of Wh: w[k] = Wh[k][quad*16 + l15] = Wh[k][lane] ----
    float w[16];
    #pragma unroll
    for (int k = 0; k < 16; ++k) w[k] = Wh[(size_t)k * 64 + lane];

    // ---- Wx as MFMA B-fragments (bf16), loaded once ----
    // B[k = kc*32 + quad*8 + jj][n = nt*16 + l15] = Wx[k][n]
    bf16x8 wxf[4][2];
    #pragma unroll
    for (int nt = 0; nt < 4; ++nt)
        #pragma unroll
        for (int kc = 0; kc < 2; ++kc)
            #pragma unroll
            for (int jj = 0; jj < 8; ++jj)
                wxf[nt][kc][jj] =
                    (short)f2bf(Wx[(size_t)(kc * 32 + quad * 8 + jj) * 64 + nt * 16 + l15]);

    // bias per lane for projection: gate column g = nt*16 + l15
    float bv[4];
    #pragma unroll
    for (int nt = 0; nt < 4; ++nt) bv[nt] = bias[nt * 16 + l15];

    // ---- x tile staging registers: [kc*2 + half], 4 float4 (one row) ----
    float4 xn[4];
    auto load_tile = [&](int t0) {
        const float* p = x + ((size_t)b * Tdim + t0 + l15) * 64 + quad * 8;
        xn[0] = *(const float4*)(p);
        xn[1] = *(const float4*)(p + 4);
        xn[2] = *(const float4*)(p + 32);
        xn[3] = *(const float4*)(p + 36);
    };

    // Project current xn (one 16-step tile) into LDS buffer q.
    // D[m = quad*4 + reg][n = nt*16 + l15] -> t = quad*4+reg, unit = l15,
    // gate = nt. {i,f,g,o} of (t, unit) are acc[0..3][reg] -> one b128 write.
    auto project = [&](int q) {
        bf16x8 af[2];
        #pragma unroll
        for (int kc = 0; kc < 2; ++kc) {
            const float4 p0 = xn[kc * 2], p1 = xn[kc * 2 + 1];
            af[kc][0] = (short)f2bf(p0.x); af[kc][1] = (short)f2bf(p0.y);
            af[kc][2] = (short)f2bf(p0.z); af[kc][3] = (short)f2bf(p0.w);
            af[kc][4] = (short)f2bf(p1.x); af[kc][5] = (short)f2bf(p1.y);
            af[kc][6] = (short)f2bf(p1.z); af[kc][7] = (short)f2bf(p1.w);
        }
        f32x4 acc[4];
        #pragma unroll
        for (int nt = 0; nt < 4; ++nt) {
            f32x4 a = {bv[nt], bv[nt], bv[nt], bv[nt]};
            a = __builtin_amdgcn_mfma_f32_16x16x32_bf16(af[0], wxf[nt][0], a, 0, 0, 0);
            a = __builtin_amdgcn_mfma_f32_16x16x32_bf16(af[1], wxf[nt][1], a, 0, 0, 0);
            acc[nt] = a;
        }
        #pragma unroll
        for (int reg = 0; reg < 4; ++reg) {
            float4 w4;
            w4.x = acc[0][reg]; w4.y = acc[1][reg];
            w4.z = acc[2][reg]; w4.w = acc[3][reg];
            *(float4*)&zbuf[q * BUFD + (quad * 4 + reg) * TSTRIDE + l15 * 4] = w4;
        }
    };

    // Scan-side z read: lane (g=quad, j=l15) wants z[t][j][g] (scalar).
    // Bank = (4*j + g) mod 32 over lanes -> exactly 2 lanes/bank = free.
    const int zoff = l15 * 4 + quad;
    auto readz = [&](int q, int t) -> float {
        return zbuf[q * BUFD + t * TSTRIDE + zoff];
    };

    // ---- prologue: block 0 projected, block 1 loads in flight ----
    load_tile(0);
    project(0);
    load_tile(16);

    float c = 0.f, h = 0.f;
    float hk[16];
    #pragma unroll
    for (int k = 0; k < 16; ++k) hk[k] = 0.f;   // h0 = 0
    float zc = readz(0, 0);

    for (int n = 0; n < NBLK; ++n) {
        const int p = n & 1;
        if (n + 1 < NBLK) {
            project(p ^ 1);                          // consumes xn = tile n+1
            if (n + 2 < NBLK) load_tile((n + 2) * 16);  // prefetch, 16 steps slack
        }
        #pragma unroll
        for (int u = 0; u < 16; ++u) {
            // prefetch next step's z (last step: next block's t=0, other buffer)
            float zn = (u < 15) ? readz(p, u + 1) : readz(p ^ 1, 0);

            // my gate's pre-activation: two independent 8-FMA chains
            float a0 = zc, a1 = 0.f;
            #pragma unroll
            for (int k = 0; k < 8; ++k) {
                a0 = fmaf(hk[k],     w[k],     a0);
                a1 = fmaf(hk[k + 8], w[k + 8], a1);
            }
            const float z = a0 + a1;
            const float sig = sigmoidf(z);
            const float a = (quad == 2) ? fmaxf(z, 0.f) : sig;

            // gather the 4 gates of my unit j (lanes j + 16*g)
            const float i_ = __shfl(a, l15);
            const float f_ = __shfl(a, l15 + 16);
            const float g_ = __shfl(a, l15 + 32);
            const float o_ = __shfl(a, l15 + 48);

            c = fmaf(f_, c, i_ * g_);
            h = o_ * fmaxf(c, 0.f);    // h = o * relu(c_new)

            // broadcast h[0..15]: all 4 quads write the (bit-identical) value
            // to hbuf[j]; 4 b128 same-address reads broadcast it back.
            // DS pipe is in-order per wave -> no barrier needed.
            hbuf[l15] = h;
            const float4* hb = (const float4*)hbuf;
            float4 h0 = hb[0], h1 = hb[1], h2 = hb[2], h3 = hb[3];
            hk[0]  = h0.x; hk[1]  = h0.y; hk[2]  = h0.z; hk[3]  = h0.w;
            hk[4]  = h1.x; hk[5]  = h1.y; hk[6]  = h1.z; hk[7]  = h1.w;
            hk[8]  = h2.x; hk[9]  = h2.y; hk[10] = h2.z; hk[11] = h2.w;
            hk[12] = h3.x; hk[13] = h3.y; hk[14] = h3.z; hk[15] = h3.w;

            zc = zn;
        }
    }

    // ---- MLP head: hk holds h_T[0..15]; lane 0 computes the scalar head ----
    if (lane == 0) {
        float x2[8];
        #pragma unroll
        for (int k = 0; k < 8; ++k) {
            float s = b2[k];
            #pragma unroll
            for (int q = 0; q < 16; ++q) s = fmaf(hk[q], W2[(size_t)q * 8 + k], s);
            x2[k] = fmaxf(s, 0.f);
        }
        float x3[4];
        #pragma unroll
        for (int m = 0; m < 4; ++m) {
            float s = b3[m];
            #pragma unroll
            for (int k = 0; k < 8; ++k) s = fmaf(x2[k], W3[(size_t)k * 4 + m], s);
            x3[m] = fmaxf(s, 0.f);
        }
        float s = bo[0];
        #pragma unroll
        for (int m = 0; m < 4; ++m) s = fmaf(x3[m], Wo[m], s);
        out[b] = sigmoidf(s);
    }
}

extern "C" void kernel_launch(void* const* d_in, const int* in_sizes, int n_in,
                              void* d_out, int out_size, void* d_ws, size_t ws_size,
                              hipStream_t stream) {
    const float* x  = (const float*)d_in[0];
    const float* Wx = (const float*)d_in[1];
    const float* Wh = (const float*)d_in[2];
    const float* bb = (const float*)d_in[3];
    const float* W2 = (const float*)d_in[4];
    const float* b2 = (const float*)d_in[5];
    const float* W3 = (const float*)d_in[6];
    const float* b3 = (const float*)d_in[7];
    const float* Wo = (const float*)d_in[8];
    const float* bo = (const float*)d_in[9];

    // One row per single-wave block: 2048 blocks -> 2 waves/SIMD machine-wide.
    lstm_fused<<<Bdim, 64, 0, stream>>>(x, Wx, bb, Wh, W2, b2, W3, b3,
                                        Wo, bo, (float*)d_out);
}